// Round 1
// baseline (197.044 us; speedup 1.0000x reference)
//
#include <hip/hip_runtime.h>
#include <math.h>

// B=16, H=12, S=1024, D=64.  BH=192, rows = B*H*S = 196608.
// ws layout (bf16): Q[NE] | K[NE] | Vt_perm[NE] | Wo_perm_bf16[4096] |
//                   Wq_bf16[4096] | Wk_bf16[4096] | Wv_bf16[4096]
//
// KEY-PERMUTATION TRICK: within each 64-key block, P^T exits QK in C-layout;
// reinterpreting those regs as a B-fragment supplies key kappa(s) at MFMA
// slot s, kappa(s) = 32*(s>>5) + 16*((s&7)>>2) + 4*((s&31)>>3) + (s&3).
// We store Vt (and Wo for the d-axis in the fused out-proj) pre-permuted by
// kappa, so P (and O) feed MFMA directly from registers — no LDS roundtrip.
//
// R1 change: all weights pre-converted to bf16 ONCE (w_conv); proj_qkv reads
// W fragments straight from global (L1/L2-hot) instead of staging fp32->bf16
// through LDS per block. LDS 65KB->37.6KB => 4 blocks/CU, less VALU, fewer
// barriers. proj was occupancy/overhead-bound at 1.4 TB/s.

typedef __bf16 bf16x8 __attribute__((ext_vector_type(8)));
typedef float  f32x4  __attribute__((ext_vector_type(4)));

#define MFMA(a, b, c) __builtin_amdgcn_mfma_f32_16x16x32_bf16((a), (b), (c), 0, 0, 0)

static constexpr int S = 1024;
static constexpr int PAD = 72;      // 144 B row stride: 16B-aligned (b128-legal), breaks 128B aliasing
static constexpr size_t NE = 196608ull * 64ull;
// Q prescale: 1/sqrt(64) * log2(e)  -> scores arrive pre-scaled for exp2
static constexpr float QSCALE = 0.125f * 1.4426950408889634f;

__device__ inline unsigned long long pack4bf(float a, float b, float c, float d) {
    union { __bf16 h[4]; unsigned long long u; } pk;
    pk.h[0] = (__bf16)a; pk.h[1] = (__bf16)b; pk.h[2] = (__bf16)c; pk.h[3] = (__bf16)d;
    return pk.u;
}

union frag_u { bf16x8 v; unsigned long long u[2]; };

// ---------------------------------------------------------------------------
// Kernel 0: all weight conversions, once.
// blocks 0-3: Wq -> wqb (plain), 4-7: Wk -> wkb, 8-11: Wv -> wvb,
// blocks 12-15: Wo -> wob PERMUTED: wob[e][s] = Wo[e][kappa(s)].
// ---------------------------------------------------------------------------
__global__ void w_conv(const float* __restrict__ Wq, const float* __restrict__ Wk,
                       const float* __restrict__ Wv, const float* __restrict__ Wo,
                       __bf16* __restrict__ wqb, __bf16* __restrict__ wkb,
                       __bf16* __restrict__ wvb, __bf16* __restrict__ wob)
{
    const int grp = blockIdx.x >> 2;                              // 0..3: q,k,v,o
    const int p   = (((blockIdx.x & 3) * 256) + threadIdx.x) * 4; // 0..4092, 4-aligned
    if (grp == 3) {
        int e = p >> 6, s = p & 63;
        int h = s >> 5, qp = (s >> 3) & 3, tb = (s >> 2) & 1;
        int d0 = 32 * h + 16 * tb + 4 * qp;                       // kappa(s) for s&3==0
        float4 v = *(const float4*)(Wo + e * 64 + d0);
        *(unsigned long long*)(wob + p) = pack4bf(v.x, v.y, v.z, v.w);
    } else {
        const float* src = (grp == 0) ? Wq : (grp == 1) ? Wk : Wv;
        __bf16*      dst = (grp == 0) ? wqb : (grp == 1) ? wkb : wvb;
        float4 v = *(const float4*)(src + p);
        *(unsigned long long*)(dst + p) = pack4bf(v.x, v.y, v.z, v.w);
    }
}

// ---------------------------------------------------------------------------
// Kernel 1: Q/K/V projection, 128 rows/block, coalesced stores via LDS roundtrip.
// W fragments read directly from pre-converted bf16 global (L1/L2-hot) —
// no per-block weight staging. LDS = lx + lbuf = 37.6 KB -> 4 blocks/CU.
// V-path writes into kappa-permuted positions (4-key runs stay contiguous).
// ---------------------------------------------------------------------------
__global__ __launch_bounds__(256, 4) void proj_qkv(
    const float* __restrict__ x,
    const __bf16* __restrict__ wqb, const __bf16* __restrict__ wkb,
    const __bf16* __restrict__ wvb,
    const float* __restrict__ bq, const float* __restrict__ bk,
    const float* __restrict__ bv,
    __bf16* __restrict__ gq, __bf16* __restrict__ gk, __bf16* __restrict__ gvt)
{
    __shared__ __align__(16) __bf16 lx[128][PAD];
    __shared__ __align__(16) __bf16 lbuf[128][PAD];   // roundtrip; reused as [64][136] for Vt

    const int tid = threadIdx.x;
    const int row_base = blockIdx.x * 128;

    #pragma unroll
    for (int i = tid * 4; i < 8192; i += 1024) {
        float4 v = *(const float4*)(x + (size_t)row_base * 64 + i);
        int r = i >> 6, c = i & 63;
        *(unsigned long long*)&lx[r][c] = pack4bf(v.x, v.y, v.z, v.w);
    }
    __syncthreads();

    const int w = tid >> 6, lane = tid & 63, m = lane & 15, quad = lane >> 4;
    const int bh = row_base >> 10;
    const int s_base = row_base & 1023;

    bf16x8 xf[2][2];
    #pragma unroll
    for (int g = 0; g < 2; g++) {
        xf[g][0] = *(const bf16x8*)&lx[w * 32 + g * 16 + m][quad * 8];
        xf[g][1] = *(const bf16x8*)&lx[w * 32 + g * 16 + m][32 + quad * 8];
    }

    #pragma unroll
    for (int mtx = 0; mtx < 2; mtx++) {
        const __bf16* wb = (mtx == 0) ? wqb : wkb;
        const float*  bb = (mtx == 0) ? bq  : bk;
        #pragma unroll
        for (int et = 0; et < 4; et++) {
            bf16x8 wf0 = *(const bf16x8*)(wb + (size_t)(et * 16 + m) * 64 + quad * 8);
            bf16x8 wf1 = *(const bf16x8*)(wb + (size_t)(et * 16 + m) * 64 + 32 + quad * 8);
            float4 bias = *(const float4*)(bb + et * 16 + quad * 4);
            #pragma unroll
            for (int g = 0; g < 2; g++) {
                f32x4 acc = {0.f, 0.f, 0.f, 0.f};
                acc = MFMA(wf0, xf[g][0], acc);
                acc = MFMA(wf1, xf[g][1], acc);
                unsigned long long u;
                if (mtx == 0)
                    u = pack4bf((acc[0] + bias.x) * QSCALE, (acc[1] + bias.y) * QSCALE,
                                (acc[2] + bias.z) * QSCALE, (acc[3] + bias.w) * QSCALE);
                else
                    u = pack4bf(acc[0] + bias.x, acc[1] + bias.y,
                                acc[2] + bias.z, acc[3] + bias.w);
                *(unsigned long long*)&lbuf[w * 32 + g * 16 + m][et * 16 + quad * 4] = u;
            }
        }
        __syncthreads();
        __bf16* dst = (mtx == 0 ? gq : gk);
        #pragma unroll
        for (int it = 0; it < 4; it++) {
            int idx = it * 256 + tid;
            int row = idx >> 3, col = (idx & 7) * 8;
            *(uint4*)(dst + ((size_t)row_base + row) * 64 + col) = *(uint4*)&lbuf[row][col];
        }
        __syncthreads();
    }

    // V path: rows s_local = w*32+g*16+quad*4+r, written to kappa-permuted pos.
    __bf16 (*lvt)[136] = (__bf16(*)[136])&lbuf[0][0];
    #pragma unroll
    for (int et = 0; et < 4; et++) {
        bf16x8 wf0 = *(const bf16x8*)(wvb + (size_t)(et * 16 + m) * 64 + quad * 8);
        bf16x8 wf1 = *(const bf16x8*)(wvb + (size_t)(et * 16 + m) * 64 + 32 + quad * 8);
        const float bias = bv[et * 16 + m];
        #pragma unroll
        for (int g = 0; g < 2; g++) {
            f32x4 acc = {0.f, 0.f, 0.f, 0.f};
            acc = MFMA(xf[g][0], wf0, acc);
            acc = MFMA(xf[g][1], wf1, acc);
            // key group: group64 = w>>1, t' = (2w+g)&3, q' = quad
            const int tp = (2 * w + g) & 3;
            const int p0 = 64 * (w >> 1) + 32 * (tp >> 1) + 8 * quad + 4 * (tp & 1);
            *(unsigned long long*)&lvt[et * 16 + m][p0] =
                pack4bf(acc[0] + bias, acc[1] + bias, acc[2] + bias, acc[3] + bias);
        }
    }
    __syncthreads();
    #pragma unroll
    for (int it = 0; it < 4; it++) {
        int idx = it * 256 + tid;
        int row = idx >> 4, col = (idx & 15) * 8;
        *(uint4*)(gvt + ((size_t)bh * 64 + row) * 1024 + s_base + col) = *(uint4*)&lvt[row][col];
    }
}

// ---------------------------------------------------------------------------
// Kernel 2: flash attention + fused output projection.  Unchanged this round.
// 2-barrier shared K/V staging, g-pairs; P^T and O^T feed MFMA directly from
// registers (kappa-permuted Vt/Wo).  LDS = lk + lv = 18.4 KB.
// Grid (192 bh, 4 qb) -> same-bh same-XCD.
// ---------------------------------------------------------------------------
__global__ __launch_bounds__(256) void attn(
    const __bf16* __restrict__ gq, const __bf16* __restrict__ gk,
    const __bf16* __restrict__ gvt, const __bf16* __restrict__ wob,
    const float* __restrict__ bo, float* __restrict__ out)
{
    __shared__ __align__(16) __bf16 lk[64][PAD];        // K tile [key][d]
    __shared__ __align__(16) __bf16 lv[64][PAD];        // Vt tile [d][key-perm]

    const int tid = threadIdx.x;
    const int w = tid >> 6, lane = tid & 63, m = lane & 15, quad = lane >> 4;
    const int bh = blockIdx.x;
    const int q0 = blockIdx.y * 256 + w * 64;

    bf16x8 qf[4][2];
    #pragma unroll
    for (int g = 0; g < 4; g++) {
        const __bf16* qrow = gq + ((size_t)bh * S + q0 + g * 16 + m) * 64;
        qf[g][0] = *(const bf16x8*)(qrow + quad * 8);
        qf[g][1] = *(const bf16x8*)(qrow + 32 + quad * 8);
    }

    f32x4 o[4][4];
    float lsum[4] = {0.f, 0.f, 0.f, 0.f};
    #pragma unroll
    for (int g = 0; g < 4; g++)
        #pragma unroll
        for (int n = 0; n < 4; n++) o[g][n] = {0.f, 0.f, 0.f, 0.f};

    const int sr = tid >> 3;            // 0..31
    const int sc = (tid & 7) * 8;       // 16B chunk col
    const __bf16* kbase = gk + (size_t)bh * S * 64;
    const __bf16* vbase = gvt + (size_t)bh * 64 * 1024;

    uint4 kreg0 = *(const uint4*)(kbase + (size_t)sr * 64 + sc);
    uint4 kreg1 = *(const uint4*)(kbase + (size_t)(sr + 32) * 64 + sc);
    uint4 vreg0 = *(const uint4*)(vbase + (size_t)sr * 1024 + sc);
    uint4 vreg1 = *(const uint4*)(vbase + (size_t)(sr + 32) * 1024 + sc);

    for (int kb = 0; kb < 16; kb++) {
        __syncthreads();
        *(uint4*)&lk[sr][sc]      = kreg0;
        *(uint4*)&lk[sr + 32][sc] = kreg1;
        *(uint4*)&lv[sr][sc]      = vreg0;
        *(uint4*)&lv[sr + 32][sc] = vreg1;
        if (kb < 15) {
            const int nb = (kb + 1) * 64;
            kreg0 = *(const uint4*)(kbase + (size_t)(nb + sr) * 64 + sc);
            kreg1 = *(const uint4*)(kbase + (size_t)(nb + sr + 32) * 64 + sc);
            vreg0 = *(const uint4*)(vbase + (size_t)sr * 1024 + nb + sc);
            vreg1 = *(const uint4*)(vbase + (size_t)(sr + 32) * 1024 + nb + sc);
        }
        __syncthreads();

        #pragma unroll
        for (int gp = 0; gp < 2; gp++) {
            // QK -> exp2 -> pack P^T straight into B-fragments (no LDS)
            frag_u pb[2][2];
            #pragma unroll
            for (int t = 0; t < 4; t++) {
                bf16x8 ka0 = *(const bf16x8*)&lk[t * 16 + m][quad * 8];
                bf16x8 ka1 = *(const bf16x8*)&lk[t * 16 + m][32 + quad * 8];
                #pragma unroll
                for (int gl = 0; gl < 2; gl++) {
                    const int g = gp * 2 + gl;
                    f32x4 acc = {0.f, 0.f, 0.f, 0.f};
                    acc = MFMA(ka0, qf[g][0], acc);
                    acc = MFMA(ka1, qf[g][1], acc);
                    float e0 = __builtin_amdgcn_exp2f(acc[0]);
                    float e1 = __builtin_amdgcn_exp2f(acc[1]);
                    float e2 = __builtin_amdgcn_exp2f(acc[2]);
                    float e3 = __builtin_amdgcn_exp2f(acc[3]);
                    lsum[g] += (e0 + e1) + (e2 + e3);
                    pb[gl][t >> 1].u[t & 1] = pack4bf(e0, e1, e2, e3);
                }
            }
            // PV: O^T[d][q] += Vt_perm (A) * P^T-regs (B)
            #pragma unroll
            for (int n = 0; n < 4; n++) {
                bf16x8 va0 = *(const bf16x8*)&lv[n * 16 + m][quad * 8];
                bf16x8 va1 = *(const bf16x8*)&lv[n * 16 + m][32 + quad * 8];
                #pragma unroll
                for (int gl = 0; gl < 2; gl++) {
                    const int g = gp * 2 + gl;
                    o[g][n] = MFMA(va0, pb[gl][0].v, o[g][n]);
                    o[g][n] = MFMA(va1, pb[gl][1].v, o[g][n]);
                }
            }
        }
    }

    // ---- epilogue: l reduce, O^T regs -> A-fragments, fused @ Wo_perm + bo ----
    #pragma unroll
    for (int g = 0; g < 4; g++) {
        lsum[g] += __shfl_xor(lsum[g], 16);
        lsum[g] += __shfl_xor(lsum[g], 32);
    }

    bf16x8 wf[4][2];
    #pragma unroll
    for (int et = 0; et < 4; et++) {
        wf[et][0] = *(const bf16x8*)(wob + (size_t)(et * 16 + m) * 64 + quad * 8);
        wf[et][1] = *(const bf16x8*)(wob + (size_t)(et * 16 + m) * 64 + 32 + quad * 8);
    }
    float biasr[4];
    #pragma unroll
    for (int et = 0; et < 4; et++) biasr[et] = bo[et * 16 + m];

    #pragma unroll
    for (int g = 0; g < 4; g++) {
        const float inv = 1.f / lsum[g];
        frag_u af0, af1;
        af0.u[0] = pack4bf(o[g][0][0] * inv, o[g][0][1] * inv, o[g][0][2] * inv, o[g][0][3] * inv);
        af0.u[1] = pack4bf(o[g][1][0] * inv, o[g][1][1] * inv, o[g][1][2] * inv, o[g][1][3] * inv);
        af1.u[0] = pack4bf(o[g][2][0] * inv, o[g][2][1] * inv, o[g][2][2] * inv, o[g][2][3] * inv);
        af1.u[1] = pack4bf(o[g][3][0] * inv, o[g][3][1] * inv, o[g][3][2] * inv, o[g][3][3] * inv);
        #pragma unroll
        for (int et = 0; et < 4; et++) {
            f32x4 acc = {0.f, 0.f, 0.f, 0.f};
            acc = MFMA(af0.v, wf[et][0], acc);
            acc = MFMA(af1.v, wf[et][1], acc);
            #pragma unroll
            for (int r = 0; r < 4; r++) {
                size_t row = (size_t)bh * S + q0 + g * 16 + quad * 4 + r;
                out[row * 64 + et * 16 + m] = acc[r] + biasr[et];
            }
        }
    }
}

// ---------------------------------------------------------------------------
extern "C" void kernel_launch(void* const* d_in, const int* in_sizes, int n_in,
                              void* d_out, int out_size, void* d_ws, size_t ws_size,
                              hipStream_t stream) {
    const float* x  = (const float*)d_in[0];
    const float* Wq = (const float*)d_in[1];
    const float* bq = (const float*)d_in[2];
    const float* Wk = (const float*)d_in[3];
    const float* bk = (const float*)d_in[4];
    const float* Wv = (const float*)d_in[5];
    const float* bv = (const float*)d_in[6];
    const float* Wo = (const float*)d_in[7];
    const float* bo = (const float*)d_in[8];
    float* out = (float*)d_out;

    __bf16* gq  = (__bf16*)d_ws;
    __bf16* gk  = gq + NE;
    __bf16* gvt = gk + NE;
    __bf16* wob = gvt + NE;
    __bf16* wqb = wob + 4096;
    __bf16* wkb = wqb + 4096;
    __bf16* wvb = wkb + 4096;

    w_conv<<<16, 256, 0, stream>>>(Wq, Wk, Wv, Wo, wqb, wkb, wvb, wob);
    proj_qkv<<<1536, 256, 0, stream>>>(x, wqb, wkb, wvb, bq, bk, bv, gq, gk, gvt);
    attn<<<dim3(192, 4), 256, 0, stream>>>(gq, gk, gvt, wob, bo, out);
}

// Round 2
// 195.889 us; speedup vs baseline: 1.0059x; 1.0059x over previous
//
#include <hip/hip_runtime.h>
#include <math.h>

// B=16, H=12, S=1024, D=64.  BH=192, rows = B*H*S = 196608.
// R2: FULLY FUSED. ws layout (bf16): xb[NE] | Wo_perm[4096] | Wq[4096] | Wk[4096] | Wv[4096]
//
// prep: x fp32 -> bf16 once (+ weight conversions).  attn: per (bh,qb) block,
// Q is projected in a prologue (proj's exact MFMA + LDS roundtrip), and per
// 64-key step the K tile and kappa-permuted Vt tile are projected into LDS on
// the fly (proj's exact index math with tile index t = w).  No QKV HBM
// round-trip.  K/V proj redundancy across the 4 qb blocks is +25% MFMA, paid
// from a 27%-utilized matrix pipe; xb re-reads are same-XCD L2 hits.
//
// KEY-PERMUTATION TRICK (unchanged): P^T exits QK in C-layout; reinterpreted
// as a B-fragment it supplies key kappa(s) at MFMA k-slot s.  Vt and Wo are
// stored pre-permuted by kappa so P and O feed MFMA straight from registers.
// kappa (as implemented): s = 16t + 4q + r  ->  32*(t>>1) + 8*q + 4*(t&1) + r.

typedef __bf16 bf16x8 __attribute__((ext_vector_type(8)));
typedef float  f32x4  __attribute__((ext_vector_type(4)));

#define MFMA(a, b, c) __builtin_amdgcn_mfma_f32_16x16x32_bf16((a), (b), (c), 0, 0, 0)

static constexpr int S = 1024;
static constexpr int PAD = 72;      // 144 B row stride: 16B-aligned, breaks 128B aliasing
static constexpr size_t NE = 196608ull * 64ull;
// Q prescale: 1/sqrt(64) * log2(e)  -> scores arrive pre-scaled for exp2
static constexpr float QSCALE = 0.125f * 1.4426950408889634f;

__device__ inline unsigned long long pack4bf(float a, float b, float c, float d) {
    union { __bf16 h[4]; unsigned long long u; } pk;
    pk.h[0] = (__bf16)a; pk.h[1] = (__bf16)b; pk.h[2] = (__bf16)c; pk.h[3] = (__bf16)d;
    return pk.u;
}

union frag_u { bf16x8 v; unsigned long long u[2]; };

// ---------------------------------------------------------------------------
// Kernel 0: prep.  blocks 0..6143: x fp32 -> bf16 (8 elems/thread, exact).
// blocks 6144..6159: weight conversions (Wq/Wk/Wv plain, Wo kappa-permuted).
// ---------------------------------------------------------------------------
__global__ void prep(const float* __restrict__ x,
                     const float* __restrict__ Wq, const float* __restrict__ Wk,
                     const float* __restrict__ Wv, const float* __restrict__ Wo,
                     __bf16* __restrict__ xb,
                     __bf16* __restrict__ wqb, __bf16* __restrict__ wkb,
                     __bf16* __restrict__ wvb, __bf16* __restrict__ wob)
{
    const int bid = blockIdx.x;
    if (bid < 6144) {
        size_t p = ((size_t)bid * 256 + threadIdx.x) * 8;
        float4 a = *(const float4*)(x + p);
        float4 b = *(const float4*)(x + p + 4);
        union { unsigned long long u64[2]; uint4 v; } pk;
        pk.u64[0] = pack4bf(a.x, a.y, a.z, a.w);
        pk.u64[1] = pack4bf(b.x, b.y, b.z, b.w);
        *(uint4*)(xb + p) = pk.v;
    } else {
        const int wb  = bid - 6144;
        const int grp = wb >> 2;                                // 0..3: q,k,v,o
        const int p   = (((wb & 3) * 256) + threadIdx.x) * 4;   // 0..4092
        if (grp == 3) {
            int e = p >> 6, s = p & 63;
            int h = s >> 5, qp = (s >> 3) & 3, tb = (s >> 2) & 1;
            int d0 = 32 * h + 16 * tb + 4 * qp;                 // kappa(s) for s&3==0
            float4 v = *(const float4*)(Wo + e * 64 + d0);
            *(unsigned long long*)(wob + p) = pack4bf(v.x, v.y, v.z, v.w);
        } else {
            const float* src = (grp == 0) ? Wq : (grp == 1) ? Wk : Wv;
            __bf16*      dst = (grp == 0) ? wqb : (grp == 1) ? wkb : wvb;
            float4 v = *(const float4*)(src + p);
            *(unsigned long long*)(dst + p) = pack4bf(v.x, v.y, v.z, v.w);
        }
    }
}

// ---------------------------------------------------------------------------
// Kernel 1: fused QKV-proj + flash attention + output projection.
// Grid (192 bh, 4 qb) x 256.  LDS = union(prologue 36.9KB, main 46KB).
// Per kb: b1 -> write staged x-keys; b2 -> K/V proj into lk/lv (+prefetch);
// b3 -> QK/exp2/PV (unchanged inner loop).
// ---------------------------------------------------------------------------
__global__ __launch_bounds__(256, 2) void attn(
    const __bf16* __restrict__ xb,
    const __bf16* __restrict__ wqb, const __bf16* __restrict__ wkb,
    const __bf16* __restrict__ wvb, const __bf16* __restrict__ wob,
    const float* __restrict__ bq, const float* __restrict__ bk,
    const float* __restrict__ bv, const float* __restrict__ bo,
    float* __restrict__ out)
{
    __shared__ __align__(16) union {
        __bf16 xq[256][PAD];            // prologue: x (q rows), then Q roundtrip
        struct {
            __bf16 w[2][64][PAD];       // Wk, Wv bf16 tiles
            __bf16 k[64][PAD];          // K tile [key][d]
            __bf16 v[64][PAD];          // Vt tile [d][key-kappa]
            __bf16 xk[64][PAD];         // x rows (keys) bf16
        } m;
    } L;

    const int tid = threadIdx.x;
    const int w = tid >> 6, lane = tid & 63, m = lane & 15, quad = lane >> 4;
    const int bh = blockIdx.x;
    const int q0 = blockIdx.y * 256 + w * 64;

    // ---- prologue: project my 256 Q rows (proj's exact math) ----
    const __bf16* xqbase = xb + ((size_t)bh * 1024 + blockIdx.y * 256) * 64;
    #pragma unroll
    for (int i = tid * 8, it = 0; it < 8; i += 2048, it++) {
        int r = i >> 6, c = i & 63;
        *(uint4*)&L.xq[r][c] = *(const uint4*)(xqbase + i);
    }
    __syncthreads();
    bf16x8 xqf[4][2];
    #pragma unroll
    for (int g = 0; g < 4; g++) {
        xqf[g][0] = *(const bf16x8*)&L.xq[w * 64 + g * 16 + m][quad * 8];
        xqf[g][1] = *(const bf16x8*)&L.xq[w * 64 + g * 16 + m][32 + quad * 8];
    }
    __syncthreads();
    #pragma unroll
    for (int et = 0; et < 4; et++) {
        bf16x8 wf0 = *(const bf16x8*)(wqb + (size_t)(et * 16 + m) * 64 + quad * 8);
        bf16x8 wf1 = *(const bf16x8*)(wqb + (size_t)(et * 16 + m) * 64 + 32 + quad * 8);
        float4 bias = *(const float4*)(bq + et * 16 + quad * 4);
        #pragma unroll
        for (int g = 0; g < 4; g++) {
            f32x4 acc = {0.f, 0.f, 0.f, 0.f};
            acc = MFMA(wf0, xqf[g][0], acc);
            acc = MFMA(wf1, xqf[g][1], acc);
            *(unsigned long long*)&L.xq[w * 64 + g * 16 + m][et * 16 + quad * 4] =
                pack4bf((acc[0] + bias.x) * QSCALE, (acc[1] + bias.y) * QSCALE,
                        (acc[2] + bias.z) * QSCALE, (acc[3] + bias.w) * QSCALE);
        }
    }
    __syncthreads();
    bf16x8 qf[4][2];
    #pragma unroll
    for (int g = 0; g < 4; g++) {
        qf[g][0] = *(const bf16x8*)&L.xq[w * 64 + g * 16 + m][quad * 8];
        qf[g][1] = *(const bf16x8*)&L.xq[w * 64 + g * 16 + m][32 + quad * 8];
    }
    __syncthreads();

    // ---- stage Wk/Wv tiles into LDS (persist across main loop) ----
    #pragma unroll
    for (int i = tid * 8, it = 0; it < 2; i += 2048, it++) {
        int r = i >> 6, c = i & 63;
        *(uint4*)&L.m.w[0][r][c] = *(const uint4*)(wkb + i);
        *(uint4*)&L.m.w[1][r][c] = *(const uint4*)(wvb + i);
    }
    float4 bkr[4];
    float  bvr[4];
    #pragma unroll
    for (int et = 0; et < 4; et++) {
        bkr[et] = *(const float4*)(bk + et * 16 + quad * 4);
        bvr[et] = bv[et * 16 + m];
    }

    f32x4 o[4][4];
    float lsum[4] = {0.f, 0.f, 0.f, 0.f};
    #pragma unroll
    for (int g = 0; g < 4; g++)
        #pragma unroll
        for (int n = 0; n < 4; n++) o[g][n] = {0.f, 0.f, 0.f, 0.f};

    // prefetch x-keys for kb=0 (bf16: 2 uint4 per thread covers 64x64)
    const __bf16* xkey = xb + (size_t)bh * 1024 * 64;
    uint4 px0 = *(const uint4*)(xkey + tid * 8);
    uint4 px1 = *(const uint4*)(xkey + 2048 + tid * 8);

    const int p0 = 32 * (w >> 1) + 8 * quad + 4 * (w & 1);   // kappa base, tile t=w

    for (int kb = 0; kb < 16; kb++) {
        __syncthreads();                                     // b1: lk/lv/xk free
        {
            int i0 = tid * 8;
            int i1 = i0 + 2048;
            *(uint4*)&L.m.xk[i0 >> 6][i0 & 63] = px0;
            *(uint4*)&L.m.xk[i1 >> 6][i1 & 63] = px1;
        }
        __syncthreads();                                     // b2
        // K/V projection for this 64-key tile; wave w owns s-tile w.
        {
            bf16x8 xk0 = *(const bf16x8*)&L.m.xk[w * 16 + m][quad * 8];
            bf16x8 xk1 = *(const bf16x8*)&L.m.xk[w * 16 + m][32 + quad * 8];
            #pragma unroll
            for (int et = 0; et < 4; et++) {
                bf16x8 kw0 = *(const bf16x8*)&L.m.w[0][et * 16 + m][quad * 8];
                bf16x8 kw1 = *(const bf16x8*)&L.m.w[0][et * 16 + m][32 + quad * 8];
                f32x4 ka = {0.f, 0.f, 0.f, 0.f};
                ka = MFMA(kw0, xk0, ka);
                ka = MFMA(kw1, xk1, ka);
                *(unsigned long long*)&L.m.k[w * 16 + m][et * 16 + quad * 4] =
                    pack4bf(ka[0] + bkr[et].x, ka[1] + bkr[et].y,
                            ka[2] + bkr[et].z, ka[3] + bkr[et].w);
                bf16x8 vw0 = *(const bf16x8*)&L.m.w[1][et * 16 + m][quad * 8];
                bf16x8 vw1 = *(const bf16x8*)&L.m.w[1][et * 16 + m][32 + quad * 8];
                f32x4 va = {0.f, 0.f, 0.f, 0.f};
                va = MFMA(xk0, vw0, va);
                va = MFMA(xk1, vw1, va);
                *(unsigned long long*)&L.m.v[et * 16 + m][p0] =
                    pack4bf(va[0] + bvr[et], va[1] + bvr[et],
                            va[2] + bvr[et], va[3] + bvr[et]);
            }
        }
        if (kb < 15) {
            const __bf16* xn = xkey + (kb + 1) * 4096;
            px0 = *(const uint4*)(xn + tid * 8);
            px1 = *(const uint4*)(xn + 2048 + tid * 8);
        }
        __syncthreads();                                     // b3
        // ---- QK -> exp2 -> PV (unchanged inner loop) ----
        #pragma unroll
        for (int gp = 0; gp < 2; gp++) {
            frag_u pb[2][2];
            #pragma unroll
            for (int t = 0; t < 4; t++) {
                bf16x8 ka0 = *(const bf16x8*)&L.m.k[t * 16 + m][quad * 8];
                bf16x8 ka1 = *(const bf16x8*)&L.m.k[t * 16 + m][32 + quad * 8];
                #pragma unroll
                for (int gl = 0; gl < 2; gl++) {
                    const int g = gp * 2 + gl;
                    f32x4 acc = {0.f, 0.f, 0.f, 0.f};
                    acc = MFMA(ka0, qf[g][0], acc);
                    acc = MFMA(ka1, qf[g][1], acc);
                    float e0 = __builtin_amdgcn_exp2f(acc[0]);
                    float e1 = __builtin_amdgcn_exp2f(acc[1]);
                    float e2 = __builtin_amdgcn_exp2f(acc[2]);
                    float e3 = __builtin_amdgcn_exp2f(acc[3]);
                    lsum[g] += (e0 + e1) + (e2 + e3);
                    pb[gl][t >> 1].u[t & 1] = pack4bf(e0, e1, e2, e3);
                }
            }
            #pragma unroll
            for (int n = 0; n < 4; n++) {
                bf16x8 va0 = *(const bf16x8*)&L.m.v[n * 16 + m][quad * 8];
                bf16x8 va1 = *(const bf16x8*)&L.m.v[n * 16 + m][32 + quad * 8];
                #pragma unroll
                for (int gl = 0; gl < 2; gl++) {
                    const int g = gp * 2 + gl;
                    o[g][n] = MFMA(va0, pb[gl][0].v, o[g][n]);
                    o[g][n] = MFMA(va1, pb[gl][1].v, o[g][n]);
                }
            }
        }
    }

    // ---- epilogue: l reduce, O^T regs -> A-fragments, fused @ Wo_perm + bo ----
    #pragma unroll
    for (int g = 0; g < 4; g++) {
        lsum[g] += __shfl_xor(lsum[g], 16);
        lsum[g] += __shfl_xor(lsum[g], 32);
    }

    bf16x8 wf[4][2];
    #pragma unroll
    for (int et = 0; et < 4; et++) {
        wf[et][0] = *(const bf16x8*)(wob + (size_t)(et * 16 + m) * 64 + quad * 8);
        wf[et][1] = *(const bf16x8*)(wob + (size_t)(et * 16 + m) * 64 + 32 + quad * 8);
    }
    float biasr[4];
    #pragma unroll
    for (int et = 0; et < 4; et++) biasr[et] = bo[et * 16 + m];

    #pragma unroll
    for (int g = 0; g < 4; g++) {
        const float inv = 1.f / lsum[g];
        frag_u af0, af1;
        af0.u[0] = pack4bf(o[g][0][0] * inv, o[g][0][1] * inv, o[g][0][2] * inv, o[g][0][3] * inv);
        af0.u[1] = pack4bf(o[g][1][0] * inv, o[g][1][1] * inv, o[g][1][2] * inv, o[g][1][3] * inv);
        af1.u[0] = pack4bf(o[g][2][0] * inv, o[g][2][1] * inv, o[g][2][2] * inv, o[g][2][3] * inv);
        af1.u[1] = pack4bf(o[g][3][0] * inv, o[g][3][1] * inv, o[g][3][2] * inv, o[g][3][3] * inv);
        #pragma unroll
        for (int et = 0; et < 4; et++) {
            f32x4 acc = {0.f, 0.f, 0.f, 0.f};
            acc = MFMA(af0.v, wf[et][0], acc);
            acc = MFMA(af1.v, wf[et][1], acc);
            #pragma unroll
            for (int r = 0; r < 4; r++) {
                size_t row = (size_t)bh * S + q0 + g * 16 + quad * 4 + r;
                out[row * 64 + et * 16 + m] = acc[r] + biasr[et];
            }
        }
    }
}

// ---------------------------------------------------------------------------
extern "C" void kernel_launch(void* const* d_in, const int* in_sizes, int n_in,
                              void* d_out, int out_size, void* d_ws, size_t ws_size,
                              hipStream_t stream) {
    const float* x  = (const float*)d_in[0];
    const float* Wq = (const float*)d_in[1];
    const float* bq = (const float*)d_in[2];
    const float* Wk = (const float*)d_in[3];
    const float* bk = (const float*)d_in[4];
    const float* Wv = (const float*)d_in[5];
    const float* bv = (const float*)d_in[6];
    const float* Wo = (const float*)d_in[7];
    const float* bo = (const float*)d_in[8];
    float* out = (float*)d_out;

    __bf16* xb  = (__bf16*)d_ws;
    __bf16* wob = xb + NE;
    __bf16* wqb = wob + 4096;
    __bf16* wkb = wqb + 4096;
    __bf16* wvb = wkb + 4096;

    prep<<<6160, 256, 0, stream>>>(x, Wq, Wk, Wv, Wo, xb, wqb, wkb, wvb, wob);
    attn<<<dim3(192, 4), 256, 0, stream>>>(xb, wqb, wkb, wvb, wob,
                                           bq, bk, bv, bo, out);
}